// Round 5
// baseline (5447.203 us; speedup 1.0000x reference)
//
#include <hip/hip_runtime.h>
#include <math.h>

// Sinkhorn loss, B=8, S=2048, P=1024, D=2, eps=0.01, 50 iters.
// Persistent kernel + per-batch IC barriers (round 4), with LDS-free phases:
//  - folded potentials: qx[s] = F2[s]-K*x2[s], qy[p] = G2[p]-K*y2[p].
//    Updates: qx = -LOG2S - LSE2(u), u = 2K<x,y> + qy   (owner x2 cancels!)
//             qy = logb2 - LSE2(w),  w = 2K<x,y> + qx
//  - lane owns (1 owner x 128-elem slice); cross-lane LSE = 3-4 shfl_xor.
//  - geometry from pristine inputs via cached loads (L1); potentials via
//    4B agent(sc1) loads straight from Infinity Cache. No ds_read in loop.

#define BB 8
#define SS 2048
#define PP 1024
#define NEG_INF -1e9f
#define LOG2S 11.0f
#define ITERS 50
#define K2E 144.269504088896f   /* 100*log2(e) */
#define TWOK 288.539008177792f  /* 200*log2(e) */

__device__ __forceinline__ float fexp2(float x) { return __builtin_amdgcn_exp2f(x); }
__device__ __forceinline__ float flog2(float x) { return __builtin_amdgcn_logf(x); }
__device__ __forceinline__ float aload(const float* p) {
  return __hip_atomic_load(p, __ATOMIC_RELAXED, __HIP_MEMORY_SCOPE_AGENT);
}
__device__ __forceinline__ void astore(float* p, float v) {
  __hip_atomic_store(p, v, __ATOMIC_RELAXED, __HIP_MEMORY_SCOPE_AGENT);
}

// 64-arrival per-batch barrier (round-4 proven). __syncthreads drains the
// wave's sc1 stores (vmcnt(0)) before lane0's arrival atomic.
__device__ __forceinline__ void batch_barrier(unsigned* ctr, unsigned target) {
  __syncthreads();
  if (threadIdx.x == 0) {
    __hip_atomic_fetch_add(ctr, 1u, __ATOMIC_RELAXED, __HIP_MEMORY_SCOPE_AGENT);
    while (__hip_atomic_load(ctr, __ATOMIC_RELAXED, __HIP_MEMORY_SCOPE_AGENT) < target)
      __builtin_amdgcn_s_sleep(1);
  }
  __syncthreads();
}

// f: block = 32 rows. wave = 8 rows x 8 col-slices; lane: row=lane>>3,
// cols j*8 + (lane&7), j=0..127.
__device__ __forceinline__ void f_phase(int bid, int t,
    const float* __restrict__ preds, const float* __restrict__ pos,
    const float* __restrict__ qy, float* __restrict__ qx) {
  int w = t >> 6, lane = t & 63;
  int bb = bid >> 6;
  int row = (bid << 5) + (w << 3) + (lane >> 3);
  int cg = lane & 7;
  float2 x = ((const float2*)preds)[row];
  float kx0 = TWOK * x.x, kx1 = TWOK * x.y;
  const float2* posb = (const float2*)pos + (bb << 10);
  const float* qyb = qy + (bb << 10);
  float u[128];
  float m0 = -3.4e38f, m1 = m0, m2 = m0, m3 = m0;
#pragma unroll
  for (int j = 0; j < 128; j += 4) {
    int c = (j << 3) + cg;
    float2 ya = posb[c], yb = posb[c + 8], yc = posb[c + 16], yd = posb[c + 24];
    float qa = aload(qyb + c), qb = aload(qyb + c + 8);
    float qc = aload(qyb + c + 16), qd = aload(qyb + c + 24);
    float u0 = fmaf(kx0, ya.x, fmaf(kx1, ya.y, qa));
    float u1 = fmaf(kx0, yb.x, fmaf(kx1, yb.y, qb));
    float u2 = fmaf(kx0, yc.x, fmaf(kx1, yc.y, qc));
    float u3 = fmaf(kx0, yd.x, fmaf(kx1, yd.y, qd));
    u[j] = u0; u[j + 1] = u1; u[j + 2] = u2; u[j + 3] = u3;
    m0 = fmaxf(m0, u0); m1 = fmaxf(m1, u1);
    m2 = fmaxf(m2, u2); m3 = fmaxf(m3, u3);
  }
  float m = fmaxf(fmaxf(m0, m1), fmaxf(m2, m3));
  m = fmaxf(m, __shfl_xor(m, 1, 64));
  m = fmaxf(m, __shfl_xor(m, 2, 64));
  m = fmaxf(m, __shfl_xor(m, 4, 64));
  float s0 = 0.0f, s1 = 0.0f, s2 = 0.0f, s3 = 0.0f;
#pragma unroll
  for (int j = 0; j < 128; j += 4) {
    s0 += fexp2(u[j] - m);
    s1 += fexp2(u[j + 1] - m);
    s2 += fexp2(u[j + 2] - m);
    s3 += fexp2(u[j + 3] - m);
  }
  float s = (s0 + s1) + (s2 + s3);
  s += __shfl_xor(s, 1, 64);
  s += __shfl_xor(s, 2, 64);
  s += __shfl_xor(s, 4, 64);
  if (cg == 0) astore(qx + row, -LOG2S - m - flog2(s));
}

// g: block = 16 cols. wave = 4 cols x 16 row-slices; lane: col=lane>>4,
// rows j*16 + (lane&15), j=0..127.
__device__ __forceinline__ void g_phase(int bid, int t,
    const float* __restrict__ preds, const float* __restrict__ pos,
    const float* __restrict__ logb2, const float* __restrict__ qx,
    float* __restrict__ qy) {
  int w = t >> 6, lane = t & 63;
  int bb = bid >> 6;
  int col = (bid << 4) + (w << 2) + (lane >> 4);
  int rg = lane & 15;
  float2 y = ((const float2*)pos)[col];
  float ky0 = TWOK * y.x, ky1 = TWOK * y.y;
  const float2* predb = (const float2*)preds + (bb << 11);
  const float* qxb = qx + (bb << 11);
  float u[128];
  float m0 = -3.4e38f, m1 = m0, m2 = m0, m3 = m0;
#pragma unroll
  for (int j = 0; j < 128; j += 4) {
    int r = (j << 4) + rg;
    float2 xa = predb[r], xb = predb[r + 16], xc = predb[r + 32], xd = predb[r + 48];
    float qa = aload(qxb + r), qb = aload(qxb + r + 16);
    float qc = aload(qxb + r + 32), qd = aload(qxb + r + 48);
    float u0 = fmaf(ky0, xa.x, fmaf(ky1, xa.y, qa));
    float u1 = fmaf(ky0, xb.x, fmaf(ky1, xb.y, qb));
    float u2 = fmaf(ky0, xc.x, fmaf(ky1, xc.y, qc));
    float u3 = fmaf(ky0, xd.x, fmaf(ky1, xd.y, qd));
    u[j] = u0; u[j + 1] = u1; u[j + 2] = u2; u[j + 3] = u3;
    m0 = fmaxf(m0, u0); m1 = fmaxf(m1, u1);
    m2 = fmaxf(m2, u2); m3 = fmaxf(m3, u3);
  }
  float m = fmaxf(fmaxf(m0, m1), fmaxf(m2, m3));
  m = fmaxf(m, __shfl_xor(m, 1, 64));
  m = fmaxf(m, __shfl_xor(m, 2, 64));
  m = fmaxf(m, __shfl_xor(m, 4, 64));
  m = fmaxf(m, __shfl_xor(m, 8, 64));
  float s0 = 0.0f, s1 = 0.0f, s2 = 0.0f, s3 = 0.0f;
#pragma unroll
  for (int j = 0; j < 128; j += 4) {
    s0 += fexp2(u[j] - m);
    s1 += fexp2(u[j + 1] - m);
    s2 += fexp2(u[j + 2] - m);
    s3 += fexp2(u[j + 3] - m);
  }
  float s = (s0 + s1) + (s2 + s3);
  s += __shfl_xor(s, 1, 64);
  s += __shfl_xor(s, 2, 64);
  s += __shfl_xor(s, 4, 64);
  s += __shfl_xor(s, 8, 64);
  if (rg == 0) astore(qy + col, aload(logb2 + col) - m - flog2(s));
}

__global__ __launch_bounds__(256, 2) void sinkhorn_all(
    const float* __restrict__ preds, const int* __restrict__ labels,
    const float* __restrict__ pos, float* __restrict__ out,
    float* __restrict__ qy, float* __restrict__ qx,
    float* __restrict__ logb2, float* __restrict__ partial,
    float* __restrict__ battot, unsigned* __restrict__ bar) {
  __shared__ int cnt[PP];        // setup histogram; reused as float scratch
  const int bid = blockIdx.x, t = threadIdx.x;
  const int bb = bid >> 6;
  unsigned* myctr = bar + bb * 16;
  unsigned* gctr = bar + 8 * 16;
  unsigned target = 0;

  // ---- setup: qy0 = -K*y2 (16 entries/block) + leader histogram ----
  if (t < 16) {
    int p = ((bid & 63) << 4) + t;
    float2 y = ((const float2*)pos)[(bb << 10) + p];
    astore(qy + (bb << 10) + p, -K2E * fmaf(y.x, y.x, y.y * y.y));
  }
  if ((bid & 63) == 0) {
#pragma unroll
    for (int k = 0; k < 4; ++k) cnt[t + (k << 8)] = 0;
    __syncthreads();
#pragma unroll
    for (int k = 0; k < 8; ++k)
      atomicAdd(&cnt[labels[(bb << 11) + t + (k << 8)] & (PP - 1)], 1);
    __syncthreads();
#pragma unroll
    for (int k = 0; k < 4; ++k) {
      int p = t + (k << 8);
      int c = cnt[p];
      astore(logb2 + (bb << 10) + p, (c > 0) ? (flog2((float)c) - LOG2S) : NEG_INF);
    }
  }
  target += 64; batch_barrier(myctr, target);

#pragma unroll 1
  for (int it = 0; it < ITERS; ++it) {
    f_phase(bid, t, preds, pos, qy, qx);
    target += 64; batch_barrier(myctr, target);
    g_phase(bid, t, preds, pos, logb2, qx, qy);
    target += 64; batch_barrier(myctr, target);
  }

  // ---- final: dist contribution; lane covers (row, 128-col slice) ----
  {
    int w = t >> 6, lane = t & 63;
    int row = (bid << 5) + (w << 3) + (lane >> 3);
    int cg = lane & 7;
    float2 x = ((const float2*)preds)[row];
    float x2 = fmaf(x.x, x.x, x.y * x.y);
    float qxv = aload(qx + row);
    const float2* posb = (const float2*)pos + (bb << 10);
    const float* qyb = qy + (bb << 10);
    float acc = 0.0f;
#pragma unroll
    for (int j = 0; j < 128; ++j) {
      int c = (j << 3) + cg;
      float2 y = posb[c];
      float qv = aload(qyb + c);
      float y2 = fmaf(y.x, y.x, y.y * y.y);
      float td = fmaf(x.y, y.y, x.x * y.x);
      float C = fmaxf(fmaf(-2.0f, td, x2 + y2), 0.0f);
      float v2 = fmaf(TWOK, td, qxv + qv);
      acc = fmaf(fexp2(v2), C, acc);
    }
#pragma unroll
    for (int off = 32; off; off >>= 1) acc += __shfl_xor(acc, off, 64);
    float* shf = (float*)cnt;
    __syncthreads();
    if (lane == 0) shf[w] = acc;
    __syncthreads();
    if (t == 0) astore(partial + bid, (shf[0] + shf[1]) + (shf[2] + shf[3]));
  }
  target += 64; batch_barrier(myctr, target);

  // ---- per-batch leader reduce, then block 0 combines 8 batches ----
  if ((bid & 63) == 0 && t < 64) {
    float pv = aload(partial + (bb << 6) + t);
#pragma unroll
    for (int off = 32; off; off >>= 1) pv += __shfl_xor(pv, off, 64);
    if (t == 0) {
      astore(battot + bb, pv);
      __builtin_amdgcn_s_waitcnt(0);
      __hip_atomic_fetch_add(gctr, 1u, __ATOMIC_RELAXED, __HIP_MEMORY_SCOPE_AGENT);
      if (bid == 0) {
        while (__hip_atomic_load(gctr, __ATOMIC_RELAXED, __HIP_MEMORY_SCOPE_AGENT) < 8u)
          __builtin_amdgcn_s_sleep(1);
        float tot = 0.0f;
#pragma unroll
        for (int i = 0; i < 8; ++i) tot += aload(battot + i);
        out[0] = tot * 0.125f;
      }
    }
  }
}

extern "C" void kernel_launch(void* const* d_in, const int* in_sizes, int n_in,
                              void* d_out, int out_size, void* d_ws, size_t ws_size,
                              hipStream_t stream) {
  const float* preds = (const float*)d_in[0];   // [B,S,2]
  const int* labels = (const int*)d_in[1];      // [B,S]
  const float* pos = (const float*)d_in[2];     // [B,P,2]
  float* out = (float*)d_out;
  char* ws = (char*)d_ws;
  unsigned* bar = (unsigned*)(ws);              // [0, 1024)
  float* qy = (float*)(ws + 1024);              // B*P floats
  float* qx = (float*)(ws + 33792);             // B*S floats
  float* logb2 = (float*)(ws + 99328);          // B*P floats
  float* partial = (float*)(ws + 132096);       // 512 floats
  float* battot = (float*)(ws + 134144);        // 8 floats

  hipMemsetAsync(bar, 0, 1024, stream);

  void* args[] = {(void*)&preds, (void*)&labels, (void*)&pos, (void*)&out,
                  (void*)&qy, (void*)&qx, (void*)&logb2, (void*)&partial,
                  (void*)&battot, (void*)&bar};
  hipError_t e = hipLaunchCooperativeKernel((const void*)sinkhorn_all,
                                            dim3(512), dim3(256), args, 0, stream);
  if (e != hipSuccess) {
    hipLaunchKernelGGL(sinkhorn_all, dim3(512), dim3(256), 0, stream,
                       preds, labels, pos, out, qy, qx, logb2, partial,
                       battot, bar);
  }
}

// Round 6
// 2323.385 us; speedup vs baseline: 2.3445x; 2.3445x over previous
//
#include <hip/hip_runtime.h>
#include <math.h>

// Sinkhorn loss, B=8, S=2048, P=1024, D=2, eps=0.01, 50 iters.
// Register-tile persistent kernel:
//  - lane owns a fixed 16s x 8p tile; a[128] = 2K<x_s,y_p> lives in regs
//    (VGPR+AGPR) for the whole kernel and is SHARED by f and g phases.
//  - folded potentials: qx[s] = F2-K*x2, qy[p] = G2-K*y2:
//      qx = -log2(S) - LSE2_p(a+qy);  qy = logb2 - LSE2_s(a+qx)
//    (owner's square cancels analytically -> inner loop = add/max/exp only)
//  - per-phase: in-lane reduce + 3 shfl + LDS wave-merge -> block partial
//    (m,s) via sc1 (2KB/block written); after the per-batch barrier each
//    block locally combines the 8 partials it needs (coalesced 64B/thread
//    sc1 reads) -> NO second barrier. 1 barrier/phase, 101 total.
//  - sc1 traffic ~9MB/phase total (vs round-5's 5.7GB per-element disaster).
// Block = 256s x 128p; batch = 8 sblk x 8 pblk = 64 blocks; 512 blocks tot.

#define BB 8
#define SS 2048
#define PP 1024
#define NEG_INF -1e9f
#define LOG2S 11.0f
#define ITERS 50
#define K2E 144.269504088896f   /* 100*log2(e) */
#define TWOK 288.539008177792f  /* 200*log2(e) */
#define INVK 0.006931471805599453f /* 1/K2E */

__device__ __forceinline__ float fexp2(float x) { return __builtin_amdgcn_exp2f(x); }
__device__ __forceinline__ float flog2(float x) { return __builtin_amdgcn_logf(x); }
__device__ __forceinline__ float aload(const float* p) {
  return __hip_atomic_load(p, __ATOMIC_RELAXED, __HIP_MEMORY_SCOPE_AGENT);
}
__device__ __forceinline__ void astore(float* p, float v) {
  __hip_atomic_store(p, v, __ATOMIC_RELAXED, __HIP_MEMORY_SCOPE_AGENT);
}
__device__ __forceinline__ float2 aload2(const float2* p) {
  union { unsigned long long u; float2 f; } c;
  c.u = __hip_atomic_load((const unsigned long long*)p, __ATOMIC_RELAXED,
                          __HIP_MEMORY_SCOPE_AGENT);
  return c.f;
}
__device__ __forceinline__ void astore2(float2* p, float2 v) {
  union { unsigned long long u; float2 f; } c;
  c.f = v;
  __hip_atomic_store((unsigned long long*)p, c.u, __ATOMIC_RELAXED,
                     __HIP_MEMORY_SCOPE_AGENT);
}

// 64-arrival per-batch barrier (round-4 proven).
__device__ __forceinline__ void batch_barrier(unsigned* ctr, unsigned target) {
  __syncthreads();
  if (threadIdx.x == 0) {
    __hip_atomic_fetch_add(ctr, 1u, __ATOMIC_RELAXED, __HIP_MEMORY_SCOPE_AGENT);
    while (__hip_atomic_load(ctr, __ATOMIC_RELAXED, __HIP_MEMORY_SCOPE_AGENT) < target)
      __builtin_amdgcn_s_sleep(1);
  }
  __syncthreads();
}

__global__ __launch_bounds__(256, 2) void sinkhorn_all(
    const float* __restrict__ preds, const int* __restrict__ labels,
    const float* __restrict__ pos, float* __restrict__ out,
    float2* __restrict__ pf, float2* __restrict__ pg,
    float* __restrict__ logb2, float* __restrict__ partial,
    float* __restrict__ battot, unsigned* __restrict__ bar) {
  // smem: [0..1023] float2 merge area (also setup histogram as int[1024]);
  //       [1024..1279] qxs; [1280..1407] qys; [1408..1411] wave sums
  __shared__ float smem[1536];
  float2* fm = (float2*)smem;      // fm[row][wp] : idx row*2+wp (row<256)
  float2* gm = (float2*)smem;      // gm[col][ws] : idx col*2+ws (col<128)
  float* qxs = smem + 1024;
  float* qys = smem + 1280;
  float* wsum = smem + 1408;

  const int bid = blockIdx.x, t = threadIdx.x;
  const int bb = bid >> 6, blk = bid & 63;
  const int sB = blk >> 3, pB = blk & 7;
  const int w = t >> 6, lane = t & 63;
  const int ws_ = w >> 1, wp = w & 1;
  const int si = lane >> 3, pi = lane & 7;
  const int sbase = sB << 8;                       // block's 256-row base
  const int pbase = pB << 7;                       // block's 128-col base
  const int srow0 = sbase + (ws_ << 7) + (si << 4);  // lane's 16 rows
  const int pcol0 = pbase + (wp << 6) + (pi << 3);   // lane's 8 cols
  const int lrow = (ws_ << 7) + (si << 4);           // local row base
  const int lcol = (wp << 6) + (pi << 3);            // local col base

  unsigned* myctr = bar + bb * 16;
  unsigned* gctr = bar + 8 * 16;
  unsigned target = 0;

  // ---- leader histogram -> logb2 (uses smem as int[1024], before merges)
  if (blk == 0) {
    int* cnt = (int*)smem;
#pragma unroll
    for (int k = 0; k < 4; ++k) cnt[t + (k << 8)] = 0;
    __syncthreads();
#pragma unroll
    for (int k = 0; k < 8; ++k)
      atomicAdd(&cnt[labels[(bb << 11) + t + (k << 8)] & (PP - 1)], 1);
    __syncthreads();
#pragma unroll
    for (int k = 0; k < 4; ++k) {
      int p = t + (k << 8);
      int c = cnt[p];
      astore(logb2 + (bb << 10) + p, (c > 0) ? (flog2((float)c) - LOG2S) : NEG_INF);
    }
    __syncthreads();
  }

  // ---- setup: geometry + static bilinear tile a[128] ----
  const float2* predb = (const float2*)preds + (bb << 11);
  const float2* posb = (const float2*)pos + (bb << 10);
  float x2[16], y2[8], qy_r[8], qx_r[16];
  float a[128];
  {
    float2 xg[16], yg[8];
#pragma unroll
    for (int k = 0; k < 16; ++k) {
      xg[k] = predb[srow0 + k];
      x2[k] = fmaf(xg[k].x, xg[k].x, xg[k].y * xg[k].y);
    }
#pragma unroll
    for (int j = 0; j < 8; ++j) {
      yg[j] = posb[pcol0 + j];
      y2[j] = fmaf(yg[j].x, yg[j].x, yg[j].y * yg[j].y);
      qy_r[j] = -K2E * y2[j];  // qy at iteration 0 (G2 == 0)
    }
#pragma unroll
    for (int k = 0; k < 16; ++k)
#pragma unroll
      for (int j = 0; j < 8; ++j)
        a[(k << 3) + j] = TWOK * fmaf(xg[k].x, yg[j].x, xg[k].y * yg[j].y);
  }

  // ---- f phase: per s-row LSE over block's 128 cols -> pf partial ----
  auto f_phase = [&]() {
#pragma unroll
    for (int k = 0; k < 16; ++k) {
      float u[8];
      float m = -3.4e38f;
#pragma unroll
      for (int j = 0; j < 8; ++j) {
        u[j] = a[(k << 3) + j] + qy_r[j];
        m = fmaxf(m, u[j]);
      }
      m = fmaxf(m, __shfl_xor(m, 1, 64));
      m = fmaxf(m, __shfl_xor(m, 2, 64));
      m = fmaxf(m, __shfl_xor(m, 4, 64));
      float s = 0.0f;
#pragma unroll
      for (int j = 0; j < 8; ++j) s += fexp2(u[j] - m);
      s += __shfl_xor(s, 1, 64);
      s += __shfl_xor(s, 2, 64);
      s += __shfl_xor(s, 4, 64);
      if (pi == 0) fm[((lrow + k) << 1) + wp] = make_float2(m, s);
    }
    __syncthreads();
    // merge 2 wp-halves, publish block partial for row sbase+t
    float2 pa = fm[t << 1], pb = fm[(t << 1) + 1];
    float M = fmaxf(pa.x, pb.x);
    float S = pa.y * fexp2(pa.x - M) + pb.y * fexp2(pb.x - M);
    astore2(&pf[(((bb << 11) + sbase + t) << 3) + pB], make_float2(M, S));
  };

  // ---- g phase: per p-col LSE over block's 256 rows -> pg partial ----
  auto g_phase = [&]() {
#pragma unroll
    for (int j = 0; j < 8; ++j) {
      float u[16];
      float m = -3.4e38f;
#pragma unroll
      for (int k = 0; k < 16; ++k) {
        u[k] = a[(k << 3) + j] + qx_r[k];
        m = fmaxf(m, u[k]);
      }
      m = fmaxf(m, __shfl_xor(m, 8, 64));
      m = fmaxf(m, __shfl_xor(m, 16, 64));
      m = fmaxf(m, __shfl_xor(m, 32, 64));
      float s = 0.0f;
#pragma unroll
      for (int k = 0; k < 16; ++k) s += fexp2(u[k] - m);
      s += __shfl_xor(s, 8, 64);
      s += __shfl_xor(s, 16, 64);
      s += __shfl_xor(s, 32, 64);
      if (si == 0) gm[((lcol + j) << 1) + ws_] = make_float2(m, s);
    }
    __syncthreads();
    if (t < 128) {
      float2 pa = gm[t << 1], pb = gm[(t << 1) + 1];
      float M = fmaxf(pa.x, pb.x);
      float S = pa.y * fexp2(pa.x - M) + pb.y * fexp2(pb.x - M);
      astore2(&pg[(((bb << 10) + pbase + t) << 3) + sB], make_float2(M, S));
    }
  };

  // ======== iteration 0 f (uses analytic qy0) ========
  f_phase();
  target += 64; batch_barrier(myctr, target);

  float logb_reg = 0.0f;  // cached by t<128 threads at first g-combine
#pragma unroll 1
  for (int it = 0; it < ITERS; ++it) {
    // ---- combine qx: thread t owns row sbase+t; read 8 pblk partials ----
    {
      const float2* src = &pf[((bb << 11) + sbase + t) << 3];
      float2 c0 = aload2(src + 0), c1 = aload2(src + 1);
      float2 c2 = aload2(src + 2), c3 = aload2(src + 3);
      float2 c4 = aload2(src + 4), c5 = aload2(src + 5);
      float2 c6 = aload2(src + 6), c7 = aload2(src + 7);
      float M = fmaxf(fmaxf(fmaxf(c0.x, c1.x), fmaxf(c2.x, c3.x)),
                      fmaxf(fmaxf(c4.x, c5.x), fmaxf(c6.x, c7.x)));
      float S = c0.y * fexp2(c0.x - M) + c1.y * fexp2(c1.x - M) +
                c2.y * fexp2(c2.x - M) + c3.y * fexp2(c3.x - M) +
                c4.y * fexp2(c4.x - M) + c5.y * fexp2(c5.x - M) +
                c6.y * fexp2(c6.x - M) + c7.y * fexp2(c7.x - M);
      qxs[t] = -LOG2S - (M + flog2(S));
      __syncthreads();
#pragma unroll
      for (int k = 0; k < 16; ++k) qx_r[k] = qxs[lrow + k];
    }

    g_phase();
    target += 64; batch_barrier(myctr, target);

    // ---- combine qy: thread t<128 owns col pbase+t; read 8 sblk partials
    {
      if (t < 128) {
        const float2* src = &pg[((bb << 10) + pbase + t) << 3];
        float2 c0 = aload2(src + 0), c1 = aload2(src + 1);
        float2 c2 = aload2(src + 2), c3 = aload2(src + 3);
        float2 c4 = aload2(src + 4), c5 = aload2(src + 5);
        float2 c6 = aload2(src + 6), c7 = aload2(src + 7);
        float M = fmaxf(fmaxf(fmaxf(c0.x, c1.x), fmaxf(c2.x, c3.x)),
                        fmaxf(fmaxf(c4.x, c5.x), fmaxf(c6.x, c7.x)));
        float S = c0.y * fexp2(c0.x - M) + c1.y * fexp2(c1.x - M) +
                  c2.y * fexp2(c2.x - M) + c3.y * fexp2(c3.x - M) +
                  c4.y * fexp2(c4.x - M) + c5.y * fexp2(c5.x - M) +
                  c6.y * fexp2(c6.x - M) + c7.y * fexp2(c7.x - M);
        if (it == 0) logb_reg = aload(logb2 + (bb << 10) + pbase + t);
        qys[t] = logb_reg - (M + flog2(S));
      }
      __syncthreads();
#pragma unroll
      for (int j = 0; j < 8; ++j) qy_r[j] = qys[lcol + j];
    }

    if (it == ITERS - 1) break;
    f_phase();
    target += 64; batch_barrier(myctr, target);
  }

  // ======== dist: sum exp2(a+qx+qy) * C over lane tile ========
  {
    float acc = 0.0f;
#pragma unroll
    for (int k = 0; k < 16; ++k)
#pragma unroll
      for (int j = 0; j < 8; ++j) {
        float av = a[(k << 3) + j];
        float C = fmaxf(x2[k] + y2[j] - av * INVK, 0.0f);
        float v2 = av + qx_r[k] + qy_r[j];
        acc = fmaf(fexp2(v2), C, acc);
      }
#pragma unroll
    for (int off = 32; off; off >>= 1) acc += __shfl_xor(acc, off, 64);
    __syncthreads();
    if (lane == 0) wsum[w] = acc;
    __syncthreads();
    if (t == 0) astore(partial + bid, (wsum[0] + wsum[1]) + (wsum[2] + wsum[3]));
  }
  target += 64; batch_barrier(myctr, target);

  // ---- per-batch leader reduce, block 0 combines 8 batches ----
  if (blk == 0 && t < 64) {
    float pv = aload(partial + (bb << 6) + t);
#pragma unroll
    for (int off = 32; off; off >>= 1) pv += __shfl_xor(pv, off, 64);
    if (t == 0) {
      astore(battot + bb, pv);
      __builtin_amdgcn_s_waitcnt(0);
      __hip_atomic_fetch_add(gctr, 1u, __ATOMIC_RELAXED, __HIP_MEMORY_SCOPE_AGENT);
      if (bid == 0) {
        while (__hip_atomic_load(gctr, __ATOMIC_RELAXED, __HIP_MEMORY_SCOPE_AGENT) < 8u)
          __builtin_amdgcn_s_sleep(1);
        float tot = 0.0f;
#pragma unroll
        for (int i = 0; i < 8; ++i) tot += aload(battot + i);
        out[0] = tot * 0.125f;
      }
    }
  }
}

extern "C" void kernel_launch(void* const* d_in, const int* in_sizes, int n_in,
                              void* d_out, int out_size, void* d_ws, size_t ws_size,
                              hipStream_t stream) {
  const float* preds = (const float*)d_in[0];   // [B,S,2]
  const int* labels = (const int*)d_in[1];      // [B,S]
  const float* pos = (const float*)d_in[2];     // [B,P,2]
  float* out = (float*)d_out;
  char* ws = (char*)d_ws;
  unsigned* bar = (unsigned*)(ws);              // [0, 1024)
  float* logb2 = (float*)(ws + 1024);           // 32 KB
  float2* pf = (float2*)(ws + 33792);           // 8*2048*8 float2 = 1 MB
  float2* pg = (float2*)(ws + 1082368);         // 8*1024*8 float2 = 512 KB
  float* partial = (float*)(ws + 1606656);      // 512 floats
  float* battot = (float*)(ws + 1608704);       // 8 floats

  hipMemsetAsync(bar, 0, 1024, stream);

  void* args[] = {(void*)&preds, (void*)&labels, (void*)&pos, (void*)&out,
                  (void*)&pf, (void*)&pg, (void*)&logb2, (void*)&partial,
                  (void*)&battot, (void*)&bar};
  hipError_t e = hipLaunchCooperativeKernel((const void*)sinkhorn_all,
                                            dim3(512), dim3(256), args, 0, stream);
  if (e != hipSuccess) {
    hipLaunchKernelGGL(sinkhorn_all, dim3(512), dim3(256), 0, stream,
                       preds, labels, pos, out, pf, pg, logb2, partial,
                       battot, bar);
  }
}

// Round 7
// 1272.137 us; speedup vs baseline: 4.2819x; 1.8264x over previous
//
#include <hip/hip_runtime.h>
#include <math.h>

// Sinkhorn loss, B=8, S=2048, P=1024, D=2, eps=0.01, 50 iters.
// Register-tile persistent kernel (round 6) with POINT-TO-POINT FLAG SYNC:
//  - no grid/batch barrier, no atomic RMW in the loop. Each block stores its
//    dense partial slab (sc1 -> IC), __syncthreads (drains all waves' vmcnt),
//    then one flag store. Consumers poll only their 8 producers' flags
//    (8 lanes, one load/round + __ballot), then load 8 dense slabs.
//  - slabs double-buffered by iteration parity; overwrite at it+2 is
//    transitively ordered after all reads at it via the flag DAG.
//  - lane owns a fixed 16s x 8p tile; a[128] = 2K<x_s,y_p> lives in regs
//    for the whole kernel, shared by f and g phases. Folded potentials:
//    qx = -log2S - LSE2_p(a+qy); qy = logb2 - LSE2_s(a+qx).
// Block = 256s x 128p; batch = 8 sblk x 8 pblk = 64 blocks; 512 blocks.

#define BB 8
#define SS 2048
#define PP 1024
#define NEG_INF -1e9f
#define LOG2S 11.0f
#define ITERS 50
#define K2E 144.269504088896f   /* 100*log2(e) */
#define TWOK 288.539008177792f  /* 200*log2(e) */
#define INVK 0.006931471805599453f /* 1/K2E */

__device__ __forceinline__ float fexp2(float x) { return __builtin_amdgcn_exp2f(x); }
__device__ __forceinline__ float flog2(float x) { return __builtin_amdgcn_logf(x); }
__device__ __forceinline__ float aload(const float* p) {
  return __hip_atomic_load(p, __ATOMIC_RELAXED, __HIP_MEMORY_SCOPE_AGENT);
}
__device__ __forceinline__ void astore(float* p, float v) {
  __hip_atomic_store(p, v, __ATOMIC_RELAXED, __HIP_MEMORY_SCOPE_AGENT);
}
__device__ __forceinline__ void astoreu(unsigned* p, unsigned v) {
  __hip_atomic_store(p, v, __ATOMIC_RELAXED, __HIP_MEMORY_SCOPE_AGENT);
}
__device__ __forceinline__ float2 aload2(const float2* p) {
  union { unsigned long long u; float2 f; } c;
  c.u = __hip_atomic_load((const unsigned long long*)p, __ATOMIC_RELAXED,
                          __HIP_MEMORY_SCOPE_AGENT);
  return c.f;
}
__device__ __forceinline__ void astore2(float2* p, float2 v) {
  union { unsigned long long u; float2 f; } c;
  c.f = v;
  __hip_atomic_store((unsigned long long*)p, c.u, __ATOMIC_RELAXED,
                     __HIP_MEMORY_SCOPE_AGENT);
}

// wave-wide poll: every lane loads *p (lanes alias their group's 8 flags);
// exit when all observed flags >= seq. No RMW, no contention.
__device__ __forceinline__ void waitp(const unsigned* p, unsigned seq) {
  for (;;) {
    unsigned v = __hip_atomic_load(p, __ATOMIC_RELAXED, __HIP_MEMORY_SCOPE_AGENT);
    if (__ballot((int)(v < seq)) == 0ULL) return;
    __builtin_amdgcn_s_sleep(2);
  }
}

__global__ __launch_bounds__(256, 2) void sinkhorn_all(
    const float* __restrict__ preds, const int* __restrict__ labels,
    const float* __restrict__ pos, float* __restrict__ out,
    float2* __restrict__ pf, float2* __restrict__ pg,
    float* __restrict__ partial, float* __restrict__ battot,
    unsigned* __restrict__ fflag, unsigned* __restrict__ gflag) {
  __shared__ float smem[1424];
  float2* fm = (float2*)smem;       // [512] float2 merge area (aliases cnt)
  float2* gm = (float2*)smem;       // [256] float2 used by g merge
  int* cnt = (int*)smem;            // [1024] histogram (pre-loop only)
  float* qxs = smem + 1024;         // [256]
  float* qys = smem + 1280;         // [128]
  float* wsum = smem + 1408;        // [4]

  const int bid = blockIdx.x, t = threadIdx.x;
  const int bb = bid >> 6, blk = bid & 63;
  const int sB = blk >> 3, pB = blk & 7;
  const int w = t >> 6, lane = t & 63;
  const int ws_ = w >> 1, wp = w & 1;
  const int si = lane >> 3, pi = lane & 7;
  const int sbase = sB << 8, pbase = pB << 7;
  const int srow0 = sbase + (ws_ << 7) + (si << 4);
  const int pcol0 = pbase + (wp << 6) + (pi << 3);
  const int lrow = (ws_ << 7) + (si << 4);
  const int lcol = (wp << 6) + (pi << 3);

  // ---- per-block histogram (redundant per block; removes a setup sync) ----
#pragma unroll
  for (int k = 0; k < 4; ++k) cnt[t + (k << 8)] = 0;
  __syncthreads();
#pragma unroll
  for (int k = 0; k < 8; ++k)
    atomicAdd(&cnt[labels[(bb << 11) + t + (k << 8)] & (PP - 1)], 1);
  __syncthreads();
  float logb_reg = NEG_INF;
  if (t < 128) {
    int c = cnt[pbase + t];
    if (c > 0) logb_reg = flog2((float)c) - LOG2S;
  }
  __syncthreads();  // cnt dead; fm/gm may reuse the space

  // ---- geometry + static bilinear tile a[128] ----
  const float2* predb = (const float2*)preds + (bb << 11);
  const float2* posb = (const float2*)pos + (bb << 10);
  float x2[16], y2[8], qy_r[8], qx_r[16];
  float a[128];
  {
    float2 xg[16], yg[8];
#pragma unroll
    for (int k = 0; k < 16; ++k) {
      xg[k] = predb[srow0 + k];
      x2[k] = fmaf(xg[k].x, xg[k].x, xg[k].y * xg[k].y);
    }
#pragma unroll
    for (int j = 0; j < 8; ++j) {
      yg[j] = posb[pcol0 + j];
      y2[j] = fmaf(yg[j].x, yg[j].x, yg[j].y * yg[j].y);
      qy_r[j] = -K2E * y2[j];  // qy at iteration 0 (G2 == 0)
    }
#pragma unroll
    for (int k = 0; k < 16; ++k)
#pragma unroll
      for (int j = 0; j < 8; ++j)
        a[(k << 3) + j] = TWOK * fmaf(xg[k].x, yg[j].x, xg[k].y * yg[j].y);
  }

  unsigned* myff = fflag + bid;
  unsigned* mygf = gflag + bid;
  const unsigned* pollf = fflag + (bb << 6) + (sB << 3) + (lane & 7);
  const unsigned* pollg = gflag + (bb << 6) + ((lane & 7) << 3) + pB;

  // f: LSE over block's 128 cols per row -> dense slab pf[par][bb][pB][row]
  auto f_phase = [&](int par, unsigned seq) {
#pragma unroll
    for (int k = 0; k < 16; ++k) {
      float u[8];
      float m = -3.4e38f;
#pragma unroll
      for (int j = 0; j < 8; ++j) {
        u[j] = a[(k << 3) + j] + qy_r[j];
        m = fmaxf(m, u[j]);
      }
      m = fmaxf(m, __shfl_xor(m, 1, 64));
      m = fmaxf(m, __shfl_xor(m, 2, 64));
      m = fmaxf(m, __shfl_xor(m, 4, 64));
      float s = 0.0f;
#pragma unroll
      for (int j = 0; j < 8; ++j) s += fexp2(u[j] - m);
      s += __shfl_xor(s, 1, 64);
      s += __shfl_xor(s, 2, 64);
      s += __shfl_xor(s, 4, 64);
      if (pi == 0) fm[((lrow + k) << 1) + wp] = make_float2(m, s);
    }
    __syncthreads();
    float2 pa = fm[t << 1], pb2 = fm[(t << 1) + 1];
    float M = fmaxf(pa.x, pb2.x);
    float S = fmaf(pa.y, fexp2(pa.x - M), pb2.y * fexp2(pb2.x - M));
    astore2(pf + ((par * 8 + bb) << 14) + (pB << 11) + sbase + t,
            make_float2(M, S));
    __syncthreads();  // drain ALL waves' slab stores (vmcnt(0) before barrier)
    if (t == 0) astoreu(myff, seq);
  };

  // g: LSE over block's 256 rows per col -> dense slab pg[par][bb][sB][col]
  auto g_phase = [&](int par, unsigned seq) {
#pragma unroll
    for (int j = 0; j < 8; ++j) {
      float u[16];
      float m = -3.4e38f;
#pragma unroll
      for (int k = 0; k < 16; ++k) {
        u[k] = a[(k << 3) + j] + qx_r[k];
        m = fmaxf(m, u[k]);
      }
      m = fmaxf(m, __shfl_xor(m, 8, 64));
      m = fmaxf(m, __shfl_xor(m, 16, 64));
      m = fmaxf(m, __shfl_xor(m, 32, 64));
      float s = 0.0f;
#pragma unroll
      for (int k = 0; k < 16; ++k) s += fexp2(u[k] - m);
      s += __shfl_xor(s, 8, 64);
      s += __shfl_xor(s, 16, 64);
      s += __shfl_xor(s, 32, 64);
      if (si == 0) gm[((lcol + j) << 1) + ws_] = make_float2(m, s);
    }
    __syncthreads();
    if (t < 128) {
      float2 pa = gm[t << 1], pb2 = gm[(t << 1) + 1];
      float M = fmaxf(pa.x, pb2.x);
      float S = fmaf(pa.y, fexp2(pa.x - M), pb2.y * fexp2(pb2.x - M));
      astore2(pg + ((par * 8 + bb) << 13) + (sB << 10) + pbase + t,
              make_float2(M, S));
    }
    __syncthreads();
    if (t == 0) astoreu(mygf, seq);
  };

  // ======== iteration 0 f (analytic qy0), flag seq 1 ========
  f_phase(0, 1);

#pragma unroll 1
  for (int it = 0; it < ITERS; ++it) {
    const int par = it & 1;
    // ---- qx combine: wait 8 f-producers (sB,*), load dense slabs ----
    waitp(pollf, (unsigned)(it + 1));
    {
      const float2* src = pf + ((par * 8 + bb) << 14) + sbase + t;
      float2 c0 = aload2(src), c1 = aload2(src + 2048);
      float2 c2 = aload2(src + 4096), c3 = aload2(src + 6144);
      float2 c4 = aload2(src + 8192), c5 = aload2(src + 10240);
      float2 c6 = aload2(src + 12288), c7 = aload2(src + 14336);
      float M = fmaxf(fmaxf(fmaxf(c0.x, c1.x), fmaxf(c2.x, c3.x)),
                      fmaxf(fmaxf(c4.x, c5.x), fmaxf(c6.x, c7.x)));
      float S = c0.y * fexp2(c0.x - M) + c1.y * fexp2(c1.x - M) +
                c2.y * fexp2(c2.x - M) + c3.y * fexp2(c3.x - M) +
                c4.y * fexp2(c4.x - M) + c5.y * fexp2(c5.x - M) +
                c6.y * fexp2(c6.x - M) + c7.y * fexp2(c7.x - M);
      qxs[t] = -LOG2S - (M + flog2(S));
    }
    __syncthreads();
#pragma unroll
    for (int k = 0; k < 16; ++k) qx_r[k] = qxs[lrow + k];

    g_phase(par, (unsigned)(it + 1));

    // ---- qy combine: wait 8 g-producers (*,pB) ----
    waitp(pollg, (unsigned)(it + 1));
    if (t < 128) {
      const float2* src = pg + ((par * 8 + bb) << 13) + pbase + t;
      float2 c0 = aload2(src), c1 = aload2(src + 1024);
      float2 c2 = aload2(src + 2048), c3 = aload2(src + 3072);
      float2 c4 = aload2(src + 4096), c5 = aload2(src + 5120);
      float2 c6 = aload2(src + 6144), c7 = aload2(src + 7168);
      float M = fmaxf(fmaxf(fmaxf(c0.x, c1.x), fmaxf(c2.x, c3.x)),
                      fmaxf(fmaxf(c4.x, c5.x), fmaxf(c6.x, c7.x)));
      float S = c0.y * fexp2(c0.x - M) + c1.y * fexp2(c1.x - M) +
                c2.y * fexp2(c2.x - M) + c3.y * fexp2(c3.x - M) +
                c4.y * fexp2(c4.x - M) + c5.y * fexp2(c5.x - M) +
                c6.y * fexp2(c6.x - M) + c7.y * fexp2(c7.x - M);
      qys[t] = logb_reg - (M + flog2(S));
    }
    __syncthreads();
#pragma unroll
    for (int j = 0; j < 8; ++j) qy_r[j] = qys[lcol + j];

    if (it < ITERS - 1) f_phase((it + 1) & 1, (unsigned)(it + 2));
  }

  // ======== dist: sum exp2(a+qx+qy) * C over lane tile ========
  {
    float acc = 0.0f;
#pragma unroll
    for (int k = 0; k < 16; ++k)
#pragma unroll
      for (int j = 0; j < 8; ++j) {
        float av = a[(k << 3) + j];
        float C = fmaxf(x2[k] + y2[j] - av * INVK, 0.0f);
        acc = fmaf(fexp2(av + qx_r[k] + qy_r[j]), C, acc);
      }
#pragma unroll
    for (int off = 32; off; off >>= 1) acc += __shfl_xor(acc, off, 64);
    __syncthreads();
    if (lane == 0) wsum[w] = acc;
    __syncthreads();
    if (t == 0) {
      astore(partial + bid, (wsum[0] + wsum[1]) + (wsum[2] + wsum[3]));
      __builtin_amdgcn_s_waitcnt(0);       // own store at IC before flag
      astoreu(mygf, (unsigned)(ITERS + 1));
    }
  }

  // ---- batch leader (blk 0, wave 0): reduce 64 partials ----
  if (blk == 0 && w == 0) {
    waitp(gflag + (bb << 6) + lane, (unsigned)(ITERS + 1));  // 64 flags
    float pv = aload(partial + (bb << 6) + lane);
#pragma unroll
    for (int off = 32; off; off >>= 1) pv += __shfl_xor(pv, off, 64);
    if (lane == 0) {
      astore(battot + bb, pv);
      __builtin_amdgcn_s_waitcnt(0);
      astoreu(fflag + (bb << 6), (unsigned)(ITERS + 1));
    }
  }
  // ---- block 0: combine 8 batch totals ----
  if (bid == 0 && w == 0) {
    waitp(fflag + ((lane & 7) << 6), (unsigned)(ITERS + 1));
    if (lane == 0) {
      float tot = 0.0f;
#pragma unroll
      for (int i = 0; i < 8; ++i) tot += aload(battot + i);
      out[0] = tot * 0.125f;
    }
  }
}

extern "C" void kernel_launch(void* const* d_in, const int* in_sizes, int n_in,
                              void* d_out, int out_size, void* d_ws, size_t ws_size,
                              hipStream_t stream) {
  const float* preds = (const float*)d_in[0];   // [B,S,2]
  const int* labels = (const int*)d_in[1];      // [B,S]
  const float* pos = (const float*)d_in[2];     // [B,P,2]
  float* out = (float*)d_out;
  char* ws = (char*)d_ws;
  unsigned* fflag = (unsigned*)(ws);            // 512 u32
  unsigned* gflag = (unsigned*)(ws + 2048);     // 512 u32
  float2* pf = (float2*)(ws + 4096);            // 2*8*8*2048 float2 = 2 MB
  float2* pg = (float2*)(ws + 2101248);         // 2*8*8*1024 float2 = 1 MB
  float* partial = (float*)(ws + 3149824);      // 512 floats
  float* battot = (float*)(ws + 3151872);       // 8 floats

  hipMemsetAsync(ws, 0, 4096, stream);  // zero both flag arrays (capturable)

  void* args[] = {(void*)&preds, (void*)&labels, (void*)&pos, (void*)&out,
                  (void*)&pf, (void*)&pg, (void*)&partial, (void*)&battot,
                  (void*)&fflag, (void*)&gflag};
  hipError_t e = hipLaunchCooperativeKernel((const void*)sinkhorn_all,
                                            dim3(512), dim3(256), args, 0, stream);
  if (e != hipSuccess) {
    // 512 blocks x 256 thr at 2 blocks/CU == exact device capacity.
    hipLaunchKernelGGL(sinkhorn_all, dim3(512), dim3(256), 0, stream,
                       preds, labels, pos, out, pf, pg, partial, battot,
                       fflag, gflag);
  }
}